// Round 3
// baseline (532.953 us; speedup 1.0000x reference)
//
#include <hip/hip_runtime.h>
#include <hip/hip_bf16.h>

#define B_ 64
#define T_ 128
#define E_ 256
#define H_ 256
#define OW_ 512   // output row width = 2*H (elements)

typedef unsigned short ushort_t;

__device__ __forceinline__ float bf2f(ushort_t u) {
    return __uint_as_float(((unsigned int)u) << 16);
}
__device__ __forceinline__ ushort_t f2bf(float f) {
    unsigned int x = __float_as_uint(f);
    unsigned int r = x + 0x7FFFu + ((x >> 16) & 1u);
    return (ushort_t)(r >> 16);
}
__device__ __forceinline__ float fast_tanh(float x) {
    // tanh(x) = 1 - 2/(exp(2x)+1); finite for all finite x (overflow -> +-1)
    float e = __expf(2.0f * x);
    return 1.0f - 2.0f * __builtin_amdgcn_rcpf(e + 1.0f);
}

// Runtime dtype detection: mask0 holds exactly {0.0,1.0}. float32 words are
// only 0x00000000/0x3F800000; bf16-pair words also hit 0x00003F80/0x3F803F80
// (p=1/4 each). Probe the first 64 words; P(misclassify bf16) = 2^-64.
__device__ __forceinline__ int detect_bf16(const unsigned int* probe, int tid,
                                           int* flag_s) {
    unsigned int w = probe[tid & 63];
    unsigned long long vote = __ballot(w == 0x00003F80u || w == 0x3F803F80u);
    if (tid == 0) *flag_s = (vote != 0ull) ? 1 : 0;
    __syncthreads();
    return *flag_s;
}

__device__ __forceinline__ float loadF(const void* p, size_t i, int isbf) {
    return isbf ? bf2f(((const ushort_t*)p)[i]) : ((const float*)p)[i];
}
__device__ __forceinline__ void storeF(void* p, size_t i, int isbf, float v) {
    if (isbf) ((ushort_t*)p)[i] = f2bf(v);
    else      ((float*)p)[i] = v;
}

// Load 128 contiguous weights (flat element offset `base`) into w[], * mask.
__device__ __forceinline__ void load_weights(float* w, const void* W,
                                             const void* M, int base, int isbf) {
    if (isbf) {
        const ushort_t* Wp = (const ushort_t*)W;
        const ushort_t* Mp = (const ushort_t*)M;
        #pragma unroll
        for (int i = 0; i < 128; i += 8) {
            union { uint4 v; ushort_t u[8]; } wv, mv;
            wv.v = *(const uint4*)(Wp + base + i);
            #pragma unroll
            for (int q = 0; q < 8; ++q) w[i + q] = bf2f(wv.u[q]);
            if (M) {
                mv.v = *(const uint4*)(Mp + base + i);
                #pragma unroll
                for (int q = 0; q < 8; ++q) w[i + q] *= bf2f(mv.u[q]);
            }
        }
    } else {
        const float* Wp = (const float*)W;
        const float* Mp = (const float*)M;
        #pragma unroll
        for (int i = 0; i < 128; i += 4) {
            float4 wv = *(const float4*)(Wp + base + i);
            w[i + 0] = wv.x; w[i + 1] = wv.y; w[i + 2] = wv.z; w[i + 3] = wv.w;
            if (M) {
                float4 mv = *(const float4*)(Mp + base + i);
                w[i+0] *= mv.x; w[i+1] *= mv.y; w[i+2] *= mv.z; w[i+3] *= mv.w;
            }
        }
    }
}

// One WG per batch row. Thread (j,half) holds masked Wrec[j][half*128..+127]
// as f32 in 128 VGPRs. h state (f32) double-buffered in LDS. xp is read with
// a one-step register prefetch so scan1 may alias xp and hout regions:
// reads of row t+1 precede the end-of-step-t barrier; writes to row t+1
// happen only after it.
__global__ __launch_bounds__(512, 2)
void ltc_scan_kernel(const void* base,          // d_out base
                     int xp_col, int out_col,   // column offsets (elements)
                     const void* __restrict__ Wrec,
                     const void* __restrict__ mask,
                     const void* __restrict__ tau_raw,
                     const unsigned int* __restrict__ probe)
{
    const int b    = blockIdx.x;
    const int tid  = threadIdx.x;   // 0..511
    const int j    = tid >> 1;      // output unit 0..255
    const int half = tid & 1;       // k-half

    __shared__ __align__(16) float h_s[2][H_];
    __shared__ int flag_s;
    const int isbf = detect_bf16(probe, tid, &flag_s);
    void* out = (void*)base;

    float w[128];
    load_weights(w, Wrec, mask, tid * 128, isbf);

    const float traw    = loadF(tau_raw, j, isbf);
    const float inv_tau = 1.0f / (logf(1.0f + __expf(traw)) + 0.1f);

    if (tid < H_) h_s[0][tid] = 0.0f;

    const size_t row0 = (size_t)b * T_ * OW_;
    float xp_cur = loadF(base, row0 + xp_col + j, isbf);  // prefetch t=0
    float h_reg  = 0.0f;
    __syncthreads();

    for (int t = 0; t < T_; ++t) {
        const int rb = t & 1;
        const float* hb = &h_s[rb][half * 128];
        float acc = 0.0f;
        #pragma unroll
        for (int i = 0; i < 128; i += 4) {
            float4 hv = *(const float4*)(hb + i);
            acc = fmaf(w[i + 0], hv.x, acc);
            acc = fmaf(w[i + 1], hv.y, acc);
            acc = fmaf(w[i + 2], hv.z, acc);
            acc = fmaf(w[i + 3], hv.w, acc);
        }
        acc += __shfl_xor(acc, 1);  // combine the two k-halves (adjacent lanes)

        const float pre   = xp_cur + acc;
        const float h_new = h_reg + (fast_tanh(pre) - h_reg) * inv_tau;
        h_reg = h_new;

        // prefetch next xp row BEFORE the barrier (ordering vs next-step writes)
        if (t + 1 < T_)
            xp_cur = loadF(base, row0 + (size_t)(t + 1) * OW_ + xp_col + j, isbf);

        if (half == 0) {
            h_s[rb ^ 1][j] = h_new;
            storeF(out, row0 + (size_t)t * OW_ + out_col + j, isbf, h_new);
        }
        __syncthreads();
    }
}

// dst[r][dst_col+j] = bias[j] + sum_d src_row(r)[src_col+d] * Wi[j][d]
// src_row(r) = src + tok[r]*src_stride (gather) or src + r*src_stride.
__global__ __launch_bounds__(512, 2)
void proj_kernel(const void* src, int src_stride, int src_col,
                 const int* __restrict__ tok,   // gather idx or null
                 const void* __restrict__ Wi,
                 const void* __restrict__ bias,
                 void* dst, int dst_col,        // row stride OW_ elements
                 int rows_per_wg,
                 const unsigned int* __restrict__ probe)
{
    const int tid  = threadIdx.x;
    const int j    = tid >> 1;
    const int half = tid & 1;
    __shared__ __align__(16) float row_s[2][E_];
    __shared__ int flag_s;
    const int isbf = detect_bf16(probe, tid, &flag_s);

    float w[128];
    load_weights(w, Wi, nullptr, tid * 128, isbf);
    const float bj = loadF(bias, j, isbf);
    const int r0 = blockIdx.x * rows_per_wg;

    if (tid < E_) {
        const size_t sb = (tok ? (size_t)tok[r0] * src_stride
                               : (size_t)r0 * src_stride) + src_col;
        row_s[0][tid] = loadF(src, sb + tid, isbf);
    }
    __syncthreads();

    for (int r = 0; r < rows_per_wg; ++r) {
        const int rb = r & 1;
        if (r + 1 < rows_per_wg && tid < E_) {   // prefetch next row
            const int rr = r0 + r + 1;
            const size_t sb = (tok ? (size_t)tok[rr] * src_stride
                                   : (size_t)rr * src_stride) + src_col;
            row_s[rb ^ 1][tid] = loadF(src, sb + tid, isbf);
        }
        const float* rp = &row_s[rb][half * 128];
        float acc = 0.0f;
        #pragma unroll
        for (int i = 0; i < 128; i += 4) {
            float4 v = *(const float4*)(rp + i);
            acc = fmaf(w[i + 0], v.x, acc);
            acc = fmaf(w[i + 1], v.y, acc);
            acc = fmaf(w[i + 2], v.z, acc);
            acc = fmaf(w[i + 3], v.w, acc);
        }
        acc += __shfl_xor(acc, 1);
        if (half == 0)
            storeF(dst, (size_t)(r0 + r) * OW_ + dst_col + j, isbf, acc + bj);
        __syncthreads();
    }
}

extern "C" void kernel_launch(void* const* d_in, const int* in_sizes, int n_in,
                              void* d_out, int out_size, void* d_ws, size_t ws_size,
                              hipStream_t stream)
{
    const int* tokens = (const int*)d_in[0];
    const void* emb    = d_in[1];
    const void* W_in0  = d_in[2];
    const void* W_rec0 = d_in[3];
    const void* b0     = d_in[4];
    const void* tau0   = d_in[5];
    const void* mask0  = d_in[6];
    const void* W_in1  = d_in[7];
    const void* W_rec1 = d_in[8];
    const void* b1     = d_in[9];
    const void* tau1   = d_in[10];
    const void* mask1  = d_in[11];
    const unsigned int* probe = (const unsigned int*)mask0;
    (void)d_ws; (void)ws_size; (void)in_sizes; (void)n_in; (void)out_size;

    const int R   = B_ * T_;  // 8192
    const int RPW = 32;       // 256 WGs
    dim3 blk(512);

    // d_out = [8192, 512] elements (dtype detected on device).
    // cols 0..255: h0 (final L0 output). cols 256..511: xp scratch, then h1.
    proj_kernel<<<dim3(R / RPW), blk, 0, stream>>>(
        emb, E_, 0, tokens, W_in0, b0, d_out, H_, RPW, probe);
    ltc_scan_kernel<<<dim3(B_), blk, 0, stream>>>(
        d_out, H_, 0, W_rec0, mask0, tau0, probe);
    proj_kernel<<<dim3(R / RPW), blk, 0, stream>>>(
        d_out, OW_, 0, nullptr, W_in1, b1, d_out, H_, RPW, probe);
    ltc_scan_kernel<<<dim3(B_), blk, 0, stream>>>(
        d_out, H_, H_, W_rec1, mask1, tau1, probe);
}

// Round 4
// 389.262 us; speedup vs baseline: 1.3691x; 1.3691x over previous
//
#include <hip/hip_runtime.h>
#include <hip/hip_bf16.h>

#define B_ 64
#define T_ 128
#define E_ 256
#define H_ 256
#define OW_ 512   // output row width = 2*H (elements)

typedef unsigned short ushort_t;

__device__ __forceinline__ float bf2f(ushort_t u) {
    return __uint_as_float(((unsigned int)u) << 16);
}
__device__ __forceinline__ ushort_t f2bf(float f) {
    unsigned int x = __float_as_uint(f);
    unsigned int r = x + 0x7FFFu + ((x >> 16) & 1u);
    return (ushort_t)(r >> 16);
}
__device__ __forceinline__ float fast_tanh(float x) {
    float e = __expf(2.0f * x);
    return 1.0f - 2.0f * __builtin_amdgcn_rcpf(e + 1.0f);
}

// Runtime dtype detection (worked in round 3): mask0 is exactly {0.0,1.0}.
// f32 words are only 0x00000000/0x3F800000; bf16-pair words also produce
// 0x00003F80/0x3F803F80 (p=1/4 each). P(misclassify bf16) = 2^-64.
__device__ __forceinline__ int detect_bf16(const unsigned int* probe, int tid,
                                           int* flag_s) {
    unsigned int w = probe[tid & 63];
    unsigned long long vote = __ballot(w == 0x00003F80u || w == 0x3F803F80u);
    if (tid == 0) *flag_s = (vote != 0ull) ? 1 : 0;
    __syncthreads();
    return *flag_s;
}

__device__ __forceinline__ float loadF(const void* p, size_t i, int isbf) {
    return isbf ? bf2f(((const ushort_t*)p)[i]) : ((const float*)p)[i];
}
__device__ __forceinline__ void storeF(void* p, size_t i, int isbf, float v) {
    if (isbf) ((ushort_t*)p)[i] = f2bf(v);
    else      ((float*)p)[i] = v;
}
__device__ __forceinline__ float4 loadF4(const void* p, size_t i, int isbf) {
    if (isbf) {
        union { uint2 u2; ushort_t u[4]; } t;
        t.u2 = *(const uint2*)((const ushort_t*)p + i);
        return make_float4(bf2f(t.u[0]), bf2f(t.u[1]), bf2f(t.u[2]), bf2f(t.u[3]));
    }
    return *(const float4*)((const float*)p + i);
}

// DPP row_ror reduction over the 16 lanes of a DPP row (our 16 k-slices are
// exactly lane bits 0..3). VALU-pipe only — no ds_swizzle LDS-pipe traffic.
template <int CTRL>
__device__ __forceinline__ float dpp_add(float v) {
    int s = __builtin_amdgcn_update_dpp(0, __float_as_int(v), CTRL, 0xF, 0xF, true);
    return v + __int_as_float(s);
}
__device__ __forceinline__ float red16(float v) {
    v = dpp_add<0x128>(v);  // row_ror:8
    v = dpp_add<0x124>(v);  // row_ror:4
    v = dpp_add<0x122>(v);  // row_ror:2
    v = dpp_add<0x121>(v);  // row_ror:1
    return v;               // all 16 lanes hold the row sum
}

// Load this thread's 4x16 weight tile (j = jg*4+r, k = ks*4 + s*64 + q).
__device__ __forceinline__ void load_tile(float w[4][16], const void* W,
                                          const void* M, int jg, int ks, int isbf) {
    #pragma unroll
    for (int r = 0; r < 4; ++r) {
        const size_t rowb = (size_t)(jg * 4 + r) * H_;
        #pragma unroll
        for (int s = 0; s < 4; ++s) {
            float4 wv = loadF4(W, rowb + s * 64 + ks * 4, isbf);
            if (M) {
                float4 mv = loadF4(M, rowb + s * 64 + ks * 4, isbf);
                wv.x *= mv.x; wv.y *= mv.y; wv.z *= mv.z; wv.w *= mv.w;
            }
            w[r][s * 4 + 0] = wv.x; w[r][s * 4 + 1] = wv.y;
            w[r][s * 4 + 2] = wv.z; w[r][s * 4 + 3] = wv.w;
        }
    }
}

// One WG (1024 threads) per batch row. Thread (jg,ks): jg=tid>>4 in [0,64),
// ks=tid&15. Owns W[jg*4..+3][ks*4 + s*64 + q] (64 weights, VGPR-resident at
// <=128 VGPR budget). Per step: 4 ds_read_b128 of h (k-interleaved: 2-way
// bank aliasing = free), 64 FMA, DPP row-reduce, epilogue on lanes ks<4.
// xp is prefetched one step ahead so scan1 may alias xp and hout regions.
__global__ __launch_bounds__(1024, 4)
void ltc_scan_kernel(const void* base, int xp_col, int out_col,
                     const void* __restrict__ Wrec,
                     const void* __restrict__ mask,
                     const void* __restrict__ tau_raw,
                     const unsigned int* __restrict__ probe)
{
    const int b   = blockIdx.x;
    const int tid = threadIdx.x;
    const int ks  = tid & 15;
    const int jg  = tid >> 4;

    __shared__ __align__(16) float h_s[2][H_];
    __shared__ int flag_s;
    const int isbf = detect_bf16(probe, tid, &flag_s);

    float w[4][16];
    load_tile(w, Wrec, mask, jg, ks, isbf);

    const int jmine = jg * 4 + (ks & 3);   // epilogue j for lanes ks<4
    const size_t row0 = (size_t)b * T_ * OW_;
    float inv_tau = 0.0f, h_prev = 0.0f, xp_cur = 0.0f;
    if (ks < 4) {
        const float traw = loadF(tau_raw, jmine, isbf);
        inv_tau = 1.0f / (logf(1.0f + __expf(traw)) + 0.1f);
        xp_cur  = loadF(base, row0 + xp_col + jmine, isbf);   // prefetch t=0
    }
    if (tid < H_) h_s[0][tid] = 0.0f;
    __syncthreads();

    for (int t = 0; t < T_; ++t) {
        const int rb = t & 1;
        const float* hp = &h_s[rb][ks * 4];
        float a0 = 0.f, a1 = 0.f, a2 = 0.f, a3 = 0.f;
        #pragma unroll
        for (int s = 0; s < 4; ++s) {
            float4 hv = *(const float4*)(hp + s * 64);
            a0 = fmaf(w[0][s*4+0], hv.x, a0); a0 = fmaf(w[0][s*4+1], hv.y, a0);
            a0 = fmaf(w[0][s*4+2], hv.z, a0); a0 = fmaf(w[0][s*4+3], hv.w, a0);
            a1 = fmaf(w[1][s*4+0], hv.x, a1); a1 = fmaf(w[1][s*4+1], hv.y, a1);
            a1 = fmaf(w[1][s*4+2], hv.z, a1); a1 = fmaf(w[1][s*4+3], hv.w, a1);
            a2 = fmaf(w[2][s*4+0], hv.x, a2); a2 = fmaf(w[2][s*4+1], hv.y, a2);
            a2 = fmaf(w[2][s*4+2], hv.z, a2); a2 = fmaf(w[2][s*4+3], hv.w, a2);
            a3 = fmaf(w[3][s*4+0], hv.x, a3); a3 = fmaf(w[3][s*4+1], hv.y, a3);
            a3 = fmaf(w[3][s*4+2], hv.z, a3); a3 = fmaf(w[3][s*4+3], hv.w, a3);
        }
        a0 = red16(a0); a1 = red16(a1); a2 = red16(a2); a3 = red16(a3);

        if (ks < 4) {
            const float sum = (ks == 0) ? a0 : (ks == 1) ? a1 : (ks == 2) ? a2 : a3;
            const float pre = xp_cur + sum;
            const float hn  = h_prev + (fast_tanh(pre) - h_prev) * inv_tau;
            h_prev = hn;
            // prefetch next xp BEFORE the barrier (aliasing safety for scan1)
            if (t + 1 < T_)
                xp_cur = loadF(base, row0 + (size_t)(t + 1) * OW_ + xp_col + jmine, isbf);
            h_s[rb ^ 1][jmine] = hn;
            storeF((void*)base, row0 + (size_t)t * OW_ + out_col + jmine, isbf, hn);
        }
        __syncthreads();
    }
}

// dst[r][dst_col + j] = bias[j] + sum_d src_row(r)[src_col + d] * Wi[j][d]
// Same 4x16 tiling; rows double-buffered through LDS with 1-row prefetch.
__global__ __launch_bounds__(1024, 4)
void proj_kernel(const void* src, int src_stride, int src_col,
                 const int* __restrict__ tok,
                 const void* __restrict__ Wi,
                 const void* __restrict__ bias,
                 void* dst, int dst_col,
                 int rows_per_wg,
                 const unsigned int* __restrict__ probe)
{
    const int tid = threadIdx.x;
    const int ks  = tid & 15;
    const int jg  = tid >> 4;

    __shared__ __align__(16) float row_s[2][E_];
    __shared__ int flag_s;
    const int isbf = detect_bf16(probe, tid, &flag_s);

    float w[4][16];
    load_tile(w, Wi, nullptr, jg, ks, isbf);

    const int jmine = jg * 4 + (ks & 3);
    float bj = 0.0f;
    if (ks < 4) bj = loadF(bias, jmine, isbf);

    const int r0 = blockIdx.x * rows_per_wg;
    if (tid < E_) {
        const size_t sb = (tok ? (size_t)tok[r0] * src_stride
                               : (size_t)r0 * src_stride) + src_col;
        row_s[0][tid] = loadF(src, sb + tid, isbf);
    }
    __syncthreads();

    for (int r = 0; r < rows_per_wg; ++r) {
        const int rb = r & 1;
        if (r + 1 < rows_per_wg && tid < E_) {   // prefetch next row
            const int rr = r0 + r + 1;
            const size_t sb = (tok ? (size_t)tok[rr] * src_stride
                                   : (size_t)rr * src_stride) + src_col;
            row_s[rb ^ 1][tid] = loadF(src, sb + tid, isbf);
        }
        const float* rp = &row_s[rb][ks * 4];
        float a0 = 0.f, a1 = 0.f, a2 = 0.f, a3 = 0.f;
        #pragma unroll
        for (int s = 0; s < 4; ++s) {
            float4 hv = *(const float4*)(rp + s * 64);
            a0 = fmaf(w[0][s*4+0], hv.x, a0); a0 = fmaf(w[0][s*4+1], hv.y, a0);
            a0 = fmaf(w[0][s*4+2], hv.z, a0); a0 = fmaf(w[0][s*4+3], hv.w, a0);
            a1 = fmaf(w[1][s*4+0], hv.x, a1); a1 = fmaf(w[1][s*4+1], hv.y, a1);
            a1 = fmaf(w[1][s*4+2], hv.z, a1); a1 = fmaf(w[1][s*4+3], hv.w, a1);
            a2 = fmaf(w[2][s*4+0], hv.x, a2); a2 = fmaf(w[2][s*4+1], hv.y, a2);
            a2 = fmaf(w[2][s*4+2], hv.z, a2); a2 = fmaf(w[2][s*4+3], hv.w, a2);
            a3 = fmaf(w[3][s*4+0], hv.x, a3); a3 = fmaf(w[3][s*4+1], hv.y, a3);
            a3 = fmaf(w[3][s*4+2], hv.z, a3); a3 = fmaf(w[3][s*4+3], hv.w, a3);
        }
        a0 = red16(a0); a1 = red16(a1); a2 = red16(a2); a3 = red16(a3);
        if (ks < 4) {
            const float sum = (ks == 0) ? a0 : (ks == 1) ? a1 : (ks == 2) ? a2 : a3;
            storeF(dst, (size_t)(r0 + r) * OW_ + dst_col + jmine, isbf, sum + bj);
        }
        __syncthreads();
    }
}

extern "C" void kernel_launch(void* const* d_in, const int* in_sizes, int n_in,
                              void* d_out, int out_size, void* d_ws, size_t ws_size,
                              hipStream_t stream)
{
    const int* tokens = (const int*)d_in[0];
    const void* emb    = d_in[1];
    const void* W_in0  = d_in[2];
    const void* W_rec0 = d_in[3];
    const void* b0     = d_in[4];
    const void* tau0   = d_in[5];
    const void* mask0  = d_in[6];
    const void* W_in1  = d_in[7];
    const void* W_rec1 = d_in[8];
    const void* b1     = d_in[9];
    const void* tau1   = d_in[10];
    const void* mask1  = d_in[11];
    const unsigned int* probe = (const unsigned int*)mask0;
    (void)d_ws; (void)ws_size; (void)in_sizes; (void)n_in; (void)out_size;

    const int R   = B_ * T_;  // 8192
    const int RPW = 32;       // 256 WGs for proj
    dim3 blk(1024);

    // d_out = [8192, 512] elements (dtype detected on device).
    // cols 0..255: h0 (final L0 output). cols 256..511: xp scratch, then h1.
    proj_kernel<<<dim3(R / RPW), blk, 0, stream>>>(
        emb, E_, 0, tokens, W_in0, b0, d_out, H_, RPW, probe);
    ltc_scan_kernel<<<dim3(B_), blk, 0, stream>>>(
        d_out, H_, 0, W_rec0, mask0, tau0, probe);
    proj_kernel<<<dim3(R / RPW), blk, 0, stream>>>(
        d_out, OW_, 0, nullptr, W_in1, b1, d_out, H_, RPW, probe);
    ltc_scan_kernel<<<dim3(B_), blk, 0, stream>>>(
        d_out, H_, H_, W_rec1, mask1, tau1, probe);
}